// Round 4
// baseline (63.432 us; speedup 1.0000x reference)
//
#include <hip/hip_runtime.h>
#include <stdint.h>

#define NUM_PIDS 20000
#define MAXBLK   512           // max per-block partial tables (adaptive to ws_size)
#define ATHREADS 1024          // accum block size: 2 blocks/CU -> 32 waves/CU
#define NCH      8             // reduce stage-1 fan-in chunks
#define FIXB     4096.0f       // 2^12 fixed point for per-hit mse
// LDS cell: count in bits[24:31], fixed-point mse sum in bits[0:23]
// stage-1 u64: count in bits[40:63], fixed-point sum in bits[0:39]

// ws layout: [ u32 tbl[nblk][NUM_PIDS] | u64 tmp[NCH][NUM_PIDS] | float acc[2] ]

__global__ void zero_acc_kernel(float* __restrict__ acc) {
    if (threadIdx.x < 2) acc[threadIdx.x] = 0.0f;
}

__device__ __forceinline__ float mse8(float4 a0, float4 a1, float4 b0, float4 b1) {
    float d0 = a0.x - b0.x, d1 = a0.y - b0.y;
    float d2 = a0.z - b0.z, d3 = a0.w - b0.w;
    float d4 = a1.x - b1.x, d5 = a1.y - b1.y;
    float d6 = a1.z - b1.z, d7 = a1.w - b1.w;
    return d0*d0 + d1*d1 + d2*d2 + d3*d3 + d4*d4 + d5*d5 + d6*d6 + d7*d7;
}

__global__ void __launch_bounds__(ATHREADS, 8) accum_kernel(
        const float4* __restrict__ pred,
        const float4* __restrict__ track,
        const int* __restrict__ pid,
        const int* __restrict__ recon,
        unsigned int* __restrict__ tbl,
        int n) {
    __shared__ unsigned int bins[NUM_PIDS];          // 80 KB -> 2 blocks/CU
    for (int j = threadIdx.x; j < NUM_PIDS; j += ATHREADS) bins[j] = 0u;
    __syncthreads();

    int tid = blockIdx.x * ATHREADS + threadIdx.x;
    int stride = gridDim.x * ATHREADS;
    // unroll x2 across stride: all 12 loads independent & unconditional,
    // so they issue together (latency hiding); accumulate is predicated.
    for (int i = tid; i < n; i += 2 * stride) {
        int i1 = i + stride;
        bool v1 = (i1 < n);
        int j1 = v1 ? i1 : i;                        // clamp keeps load in-bounds
        int p0 = pid[i],  p1 = pid[j1];
        int r0 = recon[i], r1 = recon[j1];
        float4 a00 = pred[2 * i],  a01 = pred[2 * i + 1];
        float4 b00 = track[2 * i], b01 = track[2 * i + 1];
        float4 a10 = pred[2 * j1],  a11 = pred[2 * j1 + 1];
        float4 b10 = track[2 * j1], b11 = track[2 * j1 + 1];
        float m0 = mse8(a00, a01, b00, b01);
        float m1 = mse8(a10, a11, b10, b11);
        if (p0 > 0 && r0 > 0) {
            unsigned int fx = (unsigned int)(m0 * FIXB + 0.5f);
            atomicAdd(&bins[p0], (1u << 24) | fx);
        }
        if (v1 && p1 > 0 && r1 > 0) {
            unsigned int fx = (unsigned int)(m1 * FIXB + 0.5f);
            atomicAdd(&bins[p1], (1u << 24) | fx);
        }
    }
    __syncthreads();
    // streamed coalesced flush of the whole partial table (zeros included)
    unsigned int* mytbl = tbl + (size_t)blockIdx.x * NUM_PIDS;
    for (int j = threadIdx.x; j < NUM_PIDS; j += ATHREADS) mytbl[j] = bins[j];
}

// stage 1: sum a chunk of block-tables into u64 tmp[chunk][pid]
__global__ void __launch_bounds__(256) reduce1_kernel(
        const unsigned int* __restrict__ tbl,
        unsigned long long* __restrict__ tmp,
        int nblk) {
    int p = blockIdx.x * 256 + threadIdx.x;
    int c = blockIdx.y;
    if (p >= NUM_PIDS) return;
    int cs = (nblk + NCH - 1) / NCH;
    int b0 = c * cs, b1 = min(nblk, b0 + cs);
    unsigned long long sfx = 0ULL, cnt = 0ULL;
    for (int b = b0; b < b1; ++b) {
        unsigned int v = tbl[(size_t)b * NUM_PIDS + p];   // coalesced
        sfx += (unsigned long long)(v & 0xFFFFFFu);
        cnt += (unsigned long long)(v >> 24);
    }
    tmp[(size_t)c * NUM_PIDS + p] = (cnt << 40) | sfx;
}

// stage 2: fold NCH chunks, compute per-pid mean, block-reduce, 2 atomics/block
__global__ void __launch_bounds__(256) reduce2_kernel(
        const unsigned long long* __restrict__ tmp,
        float* __restrict__ acc) {
    int p = blockIdx.x * 256 + threadIdx.x;
    float mean = 0.0f, pres = 0.0f;
    if (p >= 1 && p < NUM_PIDS) {
        unsigned long long s = 0ULL;
        #pragma unroll
        for (int c = 0; c < NCH; ++c) s += tmp[(size_t)c * NUM_PIDS + p];
        unsigned long long cnt = s >> 40;
        if (cnt > 0) {
            double sum = (double)(s & ((1ULL << 40) - 1)) * (1.0 / 4096.0);
            mean = (float)(sum / (double)cnt);
            pres = 1.0f;
        }
    }
    #pragma unroll
    for (int off = 32; off > 0; off >>= 1) {
        mean += __shfl_down(mean, off);
        pres += __shfl_down(pres, off);
    }
    __shared__ float smean[4], spres[4];
    int wave = threadIdx.x >> 6, lane = threadIdx.x & 63;
    if (lane == 0) { smean[wave] = mean; spres[wave] = pres; }
    __syncthreads();
    if (threadIdx.x == 0) {
        atomicAdd(&acc[0], smean[0] + smean[1] + smean[2] + smean[3]);
        atomicAdd(&acc[1], spres[0] + spres[1] + spres[2] + spres[3]);
    }
}

__global__ void final_kernel(const float* __restrict__ acc,
                             float* __restrict__ out) {
    if (threadIdx.x == 0 && blockIdx.x == 0) {
        float K = acc[1];
        out[0] = (K > 0.0f) ? (100.0f * acc[0] / K) : 0.0f;
    }
}

extern "C" void kernel_launch(void* const* d_in, const int* in_sizes, int n_in,
                              void* d_out, int out_size, void* d_ws, size_t ws_size,
                              hipStream_t stream) {
    // setup_inputs order: W(0) beta(1) H(2) pred(3) Y(4) particle_id(5)
    //                     track_params(6) reconstructable(7)
    const float* pred  = (const float*)d_in[3];
    const int*   pid   = (const int*)d_in[5];
    const float* track = (const float*)d_in[6];
    const int*   recon = (const int*)d_in[7];
    int n = in_sizes[5];   // N hits

    // adaptive partial-table count (one per accum block)
    size_t fixed = (size_t)NCH * NUM_PIDS * 8 + 64;
    int nblk = 8;
    if (ws_size > fixed + (size_t)NUM_PIDS * 4) {
        size_t cap = (ws_size - fixed) / ((size_t)NUM_PIDS * 4);
        nblk = (int)(cap < MAXBLK ? cap : MAXBLK);
        if (nblk < 1) nblk = 1;
    }

    unsigned int* tbl = (unsigned int*)d_ws;
    unsigned long long* tmp =
        (unsigned long long*)((char*)d_ws + (size_t)nblk * NUM_PIDS * 4);
    float* acc = (float*)((char*)tmp + (size_t)NCH * NUM_PIDS * 8);

    zero_acc_kernel<<<1, 64, 0, stream>>>(acc);
    accum_kernel<<<nblk, ATHREADS, 0, stream>>>(
        (const float4*)pred, (const float4*)track, pid, recon, tbl, n);
    dim3 g1((NUM_PIDS + 255) / 256, NCH);
    reduce1_kernel<<<g1, 256, 0, stream>>>(tbl, tmp, nblk);
    reduce2_kernel<<<(NUM_PIDS + 255) / 256, 256, 0, stream>>>(tmp, acc);
    final_kernel<<<1, 64, 0, stream>>>(acc, (float*)d_out);
}

// Round 5
// 49.634 us; speedup vs baseline: 1.2780x; 1.2780x over previous
//
#include <hip/hip_runtime.h>
#include <stdint.h>

#define NUM_PIDS 20000
#define HBLK_MAX 128           // histogram partial tables (one per hist block)
#define NCH      8             // reduce stage-1 fan-in chunks
#define FIXB     512.0f        // 2^9 fixed point for per-hit mse (17-bit field)
#define FXMASK   0x1FFFFu
// packed u32 per hit: pid in bits[17:31], fx in bits[0:16]; 0 = excluded hit
// LDS / tbl cell: count in bits[24:31], fx-sum in bits[0:23]
// tmp u64: count in bits[40:63], fx-sum in bits[0:39]

// ws: [ u32 packed[n] | u32 tbl[hblk][NUM_PIDS] | u64 tmp[NCH][NUM_PIDS] | float acc[2] ]

__global__ void zero_acc_kernel(float* __restrict__ acc) {
    if (threadIdx.x < 2) acc[threadIdx.x] = 0.0f;
}

// Pure-stream: lane t handles float4 #t (half a hit). Every load is
// lane-dense (16B stride for pred/track, duplicated-pair 4B for pid/recon),
// same shape as the 6.3 TB/s float4-copy ubench.
__global__ void __launch_bounds__(256) mse_kernel(
        const float4* __restrict__ pred,
        const float4* __restrict__ track,
        const int* __restrict__ pid,
        const int* __restrict__ recon,
        unsigned int* __restrict__ packed,
        int nf /* = 2*n float4 elements */) {
    int t = blockIdx.x * 256 + threadIdx.x;
    int stride = gridDim.x * 256;
    for (; t < nf; t += stride) {
        float4 a = pred[t], b = track[t];
        float d0 = a.x - b.x, d1 = a.y - b.y;
        float d2 = a.z - b.z, d3 = a.w - b.w;
        float part = d0*d0 + d1*d1 + d2*d2 + d3*d3;
        float mse = part + __shfl_xor(part, 1);   // combine the two half-hits
        int hit = t >> 1;
        int p = pid[hit];
        int r = recon[hit];
        unsigned int fx = (unsigned int)fminf(mse * FIXB + 0.5f, 131071.0f);
        unsigned int out = (p > 0 && r > 0) ? (((unsigned int)p << 17) | fx) : 0u;
        if ((t & 1) == 0) packed[hit] = out;      // even lane writes the hit
    }
}

__global__ void __launch_bounds__(1024) hist_kernel(
        const uint4* __restrict__ packed4,
        unsigned int* __restrict__ tbl,
        int n4,
        const unsigned int* __restrict__ packed,
        int n) {
    __shared__ unsigned int bins[NUM_PIDS];        // 80 KB -> 2 blocks/CU
    for (int j = threadIdx.x; j < NUM_PIDS; j += 1024) bins[j] = 0u;
    __syncthreads();
    int t = blockIdx.x * 1024 + threadIdx.x;
    int stride = gridDim.x * 1024;
    for (; t < n4; t += stride) {
        uint4 v = packed4[t];
        unsigned int p;
        p = v.x >> 17; if (p) atomicAdd(&bins[p], (1u << 24) | (v.x & FXMASK));
        p = v.y >> 17; if (p) atomicAdd(&bins[p], (1u << 24) | (v.y & FXMASK));
        p = v.z >> 17; if (p) atomicAdd(&bins[p], (1u << 24) | (v.z & FXMASK));
        p = v.w >> 17; if (p) atomicAdd(&bins[p], (1u << 24) | (v.w & FXMASK));
    }
    for (int i = 4 * n4 + blockIdx.x * 1024 + threadIdx.x; i < n; i += stride) {
        unsigned int c = packed[i];
        unsigned int p = c >> 17;
        if (p) atomicAdd(&bins[p], (1u << 24) | (c & FXMASK));
    }
    __syncthreads();
    unsigned int* my = tbl + (size_t)blockIdx.x * NUM_PIDS;
    for (int j = threadIdx.x; j < NUM_PIDS; j += 1024) my[j] = bins[j];
}

// stage 1: sum a chunk of block-tables into u64 tmp[chunk][pid]
__global__ void __launch_bounds__(256) reduce1_kernel(
        const unsigned int* __restrict__ tbl,
        unsigned long long* __restrict__ tmp,
        int nblk) {
    int p = blockIdx.x * 256 + threadIdx.x;
    int c = blockIdx.y;
    if (p >= NUM_PIDS) return;
    int cs = (nblk + NCH - 1) / NCH;
    int b0 = c * cs, b1 = min(nblk, b0 + cs);
    unsigned long long sfx = 0ULL, cnt = 0ULL;
    for (int b = b0; b < b1; ++b) {
        unsigned int v = tbl[(size_t)b * NUM_PIDS + p];   // coalesced
        sfx += (unsigned long long)(v & 0xFFFFFFu);
        cnt += (unsigned long long)(v >> 24);
    }
    tmp[(size_t)c * NUM_PIDS + p] = (cnt << 40) | sfx;
}

// stage 2: fold NCH chunks, per-pid mean, block-reduce, 2 atomics/block
__global__ void __launch_bounds__(256) reduce2_kernel(
        const unsigned long long* __restrict__ tmp,
        float* __restrict__ acc) {
    int p = blockIdx.x * 256 + threadIdx.x;
    float mean = 0.0f, pres = 0.0f;
    if (p >= 1 && p < NUM_PIDS) {
        unsigned long long s = 0ULL;
        #pragma unroll
        for (int c = 0; c < NCH; ++c) s += tmp[(size_t)c * NUM_PIDS + p];
        unsigned long long cnt = s >> 40;
        if (cnt > 0) {
            double sum = (double)(s & ((1ULL << 40) - 1)) * (1.0 / 512.0);
            mean = (float)(sum / (double)cnt);
            pres = 1.0f;
        }
    }
    #pragma unroll
    for (int off = 32; off > 0; off >>= 1) {
        mean += __shfl_down(mean, off);
        pres += __shfl_down(pres, off);
    }
    __shared__ float smean[4], spres[4];
    int wave = threadIdx.x >> 6, lane = threadIdx.x & 63;
    if (lane == 0) { smean[wave] = mean; spres[wave] = pres; }
    __syncthreads();
    if (threadIdx.x == 0) {
        atomicAdd(&acc[0], smean[0] + smean[1] + smean[2] + smean[3]);
        atomicAdd(&acc[1], spres[0] + spres[1] + spres[2] + spres[3]);
    }
}

__global__ void final_kernel(const float* __restrict__ acc,
                             float* __restrict__ out) {
    if (threadIdx.x == 0 && blockIdx.x == 0) {
        float K = acc[1];
        out[0] = (K > 0.0f) ? (100.0f * acc[0] / K) : 0.0f;
    }
}

extern "C" void kernel_launch(void* const* d_in, const int* in_sizes, int n_in,
                              void* d_out, int out_size, void* d_ws, size_t ws_size,
                              hipStream_t stream) {
    // setup_inputs order: W(0) beta(1) H(2) pred(3) Y(4) particle_id(5)
    //                     track_params(6) reconstructable(7)
    const float* pred  = (const float*)d_in[3];
    const int*   pid   = (const int*)d_in[5];
    const float* track = (const float*)d_in[6];
    const int*   recon = (const int*)d_in[7];
    int n = in_sizes[5];   // N hits

    size_t packed_bytes = (((size_t)n * 4) + 63) & ~(size_t)63;
    size_t tmp_bytes = (size_t)NCH * NUM_PIDS * 8;
    // adaptive histogram-table count
    int hblk = 8;
    if (ws_size > packed_bytes + tmp_bytes + 64 + (size_t)NUM_PIDS * 4) {
        size_t cap = (ws_size - packed_bytes - tmp_bytes - 64) / ((size_t)NUM_PIDS * 4);
        hblk = (int)(cap < HBLK_MAX ? cap : HBLK_MAX);
        if (hblk < 1) hblk = 1;
    }

    unsigned int* packed = (unsigned int*)d_ws;
    unsigned int* tbl = (unsigned int*)((char*)d_ws + packed_bytes);
    unsigned long long* tmp =
        (unsigned long long*)((char*)tbl + (size_t)hblk * NUM_PIDS * 4);
    float* acc = (float*)((char*)tmp + tmp_bytes);

    zero_acc_kernel<<<1, 64, 0, stream>>>(acc);
    mse_kernel<<<2048, 256, 0, stream>>>((const float4*)pred, (const float4*)track,
                                         pid, recon, packed, 2 * n);
    hist_kernel<<<hblk, 1024, 0, stream>>>((const uint4*)packed, tbl, n / 4,
                                           packed, n);
    dim3 g1((NUM_PIDS + 255) / 256, NCH);
    reduce1_kernel<<<g1, 256, 0, stream>>>(tbl, tmp, hblk);
    reduce2_kernel<<<(NUM_PIDS + 255) / 256, 256, 0, stream>>>(tmp, acc);
    final_kernel<<<1, 64, 0, stream>>>(acc, (float*)d_out);
}